// Round 1
// 359.678 us; speedup vs baseline: 1.0012x; 1.0012x over previous
//
#include <hip/hip_runtime.h>

// Problem: N=256, L=128, E=1024, H=16, D=64, S=2.  ALL float tensors are
// FP32 in memory (per harness contract: reference uses jnp.float32).
// Only q[token_index], k[sidx], v[sidx] are needed -> 5 gathered skinny GEMMs
// + 32 tiny attention heads + one 256x1024 output projection.
// Strategy: fp32 loads -> truncate to bf16 fragments -> MFMA 16x16x32_bf16
// with f32 accum (threshold is ~2% relative; trunc adds ~0.4%).
// Intermediates staged as bf16 in d_ws (1.75 MB). Final store fp32.
//
// R1 change vs 359-µs baseline: GEMM kernels restructured from 64x64-tile /
// 4-wave blocks (160 / 64 blocks -> 62% / 25% CU coverage) to 32x32-tile /
// 1-wave blocks (640 / 256 blocks -> 100% coverage) + explicit register
// double-buffer prefetch of the next K-step's fragments. attn unchanged.

#define LL 128
#define EE 1024
#define HH 16
#define DD 64
#define SS 2

typedef unsigned short u16;
typedef unsigned int   u32;
typedef __attribute__((ext_vector_type(8))) short short8;
typedef __attribute__((ext_vector_type(4))) float floatx4;

__device__ inline u32 pack_trunc(float lo, float hi) {
    return (__float_as_uint(hi) & 0xFFFF0000u) | (__float_as_uint(lo) >> 16);
}
__device__ inline u16 f2bf_rne(float f) {
    u32 u = __float_as_uint(f);
    return (u16)((u + 0x7FFFu + ((u >> 16) & 1u)) >> 16);
}
__device__ inline float bf2f(u16 x) { return __uint_as_float(((u32)x) << 16); }

// 8 consecutive fp32 at p (32B aligned) -> bf16 short8 fragment (truncate)
__device__ inline short8 frag_from_f32(const float* __restrict__ p) {
    floatx4 a = *(const floatx4*)p;
    floatx4 b = *(const floatx4*)(p + 4);
    union { short8 s; u32 w[4]; } r;
    r.w[0] = pack_trunc(a[0], a[1]);
    r.w[1] = pack_trunc(a[2], a[3]);
    r.w[2] = pack_trunc(b[0], b[1]);
    r.w[3] = pack_trunc(b[2], b[3]);
    return r.s;
}

__device__ inline int clamp_idx(int v) {            // defensive: keep in [0,256)
    return ((unsigned)v < 256u) ? v : (v & 255);
}

// ---------------------------------------------------------------------------
// Kernel 1: gathered projections, MFMA. grid (4, 32, 5): z = job.
//   job 0:   q_sel = query[tok]         @ Wq^T + bq   (128 x 1024, bf16 out)
//   job 1,2: k_sel[s] = keys[sidx[s]]   @ Wk^T + bk
//   job 3,4: v_sel[s] = values[sidx[s]] @ Wv^T + bv
// 64 thr = 1 wave per block; wave does a 32x32 tile as 2x2
// mfma_f32_16x16x32_bf16 tiles, explicit next-K prefetch double-buffer.
// A frag: lane holds A[m=lane&15][k=(lane>>4)*8+j]; B mirrors with n=lane&15.
// C/D: col=lane&15, row=(lane>>4)*4+reg  (HW-verified, guide m89/m91).
// ---------------------------------------------------------------------------
__global__ __launch_bounds__(64) void proj_mfma(
    const float* __restrict__ values, const float* __restrict__ keys,
    const float* __restrict__ query,
    const float* __restrict__ Wv, const float* __restrict__ bv,
    const float* __restrict__ Wk, const float* __restrict__ bk,
    const float* __restrict__ Wq, const float* __restrict__ bq,
    const int* __restrict__ tok, const int* __restrict__ sidx,
    u16* __restrict__ q_sel, u16* __restrict__ k_sel, u16* __restrict__ v_sel)
{
    const size_t LE = (size_t)LL * EE;
    const int job = blockIdx.z;
    const float *src, *W, *bias;
    u16* dst;
    if (job == 0)      { src = query  + (size_t)clamp_idx(tok[0])  * LE;
                         W = Wq; bias = bq; dst = q_sel; }
    else if (job <= 2) { const int s = job - 1;
                         src = keys   + (size_t)clamp_idx(sidx[s]) * LE;
                         W = Wk; bias = bk; dst = k_sel + s * LE; }
    else               { const int s = job - 3;
                         src = values + (size_t)clamp_idx(sidx[s]) * LE;
                         W = Wv; bias = bv; dst = v_sel + s * LE; }

    const int lane = threadIdx.x;
    const int lm   = lane & 15, kq = (lane >> 4) * 8;
    const int row0 = blockIdx.x * 32, col0 = blockIdx.y * 32;

    floatx4 acc[2][2] = {};
    const float* a0p = src + (size_t)(row0 + lm) * EE + kq;
    const float* a1p = a0p + 16 * EE;
    const float* b0p = W   + (size_t)(col0 + lm) * EE + kq;
    const float* b1p = b0p + 16 * EE;

    // register double-buffer: loads for step k+1 issue before step k's MFMAs
    short8 a0 = frag_from_f32(a0p), a1 = frag_from_f32(a1p);
    short8 b0 = frag_from_f32(b0p), b1 = frag_from_f32(b1p);
    for (int k0 = 32; k0 < EE; k0 += 32) {
        short8 na0 = frag_from_f32(a0p + k0);
        short8 na1 = frag_from_f32(a1p + k0);
        short8 nb0 = frag_from_f32(b0p + k0);
        short8 nb1 = frag_from_f32(b1p + k0);
        acc[0][0] = __builtin_amdgcn_mfma_f32_16x16x32_bf16(a0, b0, acc[0][0], 0, 0, 0);
        acc[0][1] = __builtin_amdgcn_mfma_f32_16x16x32_bf16(a0, b1, acc[0][1], 0, 0, 0);
        acc[1][0] = __builtin_amdgcn_mfma_f32_16x16x32_bf16(a1, b0, acc[1][0], 0, 0, 0);
        acc[1][1] = __builtin_amdgcn_mfma_f32_16x16x32_bf16(a1, b1, acc[1][1], 0, 0, 0);
        a0 = na0; a1 = na1; b0 = nb0; b1 = nb1;
    }
    acc[0][0] = __builtin_amdgcn_mfma_f32_16x16x32_bf16(a0, b0, acc[0][0], 0, 0, 0);
    acc[0][1] = __builtin_amdgcn_mfma_f32_16x16x32_bf16(a0, b1, acc[0][1], 0, 0, 0);
    acc[1][0] = __builtin_amdgcn_mfma_f32_16x16x32_bf16(a1, b0, acc[1][0], 0, 0, 0);
    acc[1][1] = __builtin_amdgcn_mfma_f32_16x16x32_bf16(a1, b1, acc[1][1], 0, 0, 0);

    const int rbase = (lane >> 4) * 4;
    #pragma unroll
    for (int i = 0; i < 2; ++i)
        #pragma unroll
        for (int j = 0; j < 2; ++j) {
            const int ccol = col0 + j * 16 + lm;
            const float bb = bias[ccol];
            #pragma unroll
            for (int r = 0; r < 4; ++r) {
                const int crow = row0 + i * 16 + rbase + r;
                dst[(size_t)crow * EE + ccol] = f2bf_rne(acc[i][j][r] + bb);
            }
        }
}

// ---------------------------------------------------------------------------
// Kernel 2: attention. grid (128, 16, 2), 64 thr = 1 wave per (q,h,s).
// q/k/v staged bf16; mask fp32 global. f32 math, width-64 reductions.
// (unchanged from baseline — controlled variable this round)
// ---------------------------------------------------------------------------
__global__ __launch_bounds__(64) void attn_simple(
    const u16* __restrict__ q_sel,   // (L, E) bf16
    const u16* __restrict__ k_sel,   // (S, L, E) bf16
    const u16* __restrict__ v_sel,   // (S, L, E) bf16
    const float* __restrict__ mask,  // (L, L) fp32
    u16* __restrict__ wv)            // (S, L, E) bf16
{
    __shared__ float p[LL];
    const int lane = threadIdx.x;
    const int q = blockIdx.x, h = blockIdx.y, s = blockIdx.z;

    const u16* Qr = q_sel + (size_t)q * EE + h * DD;
    const u16* K0 = k_sel + ((size_t)s * LL + lane) * EE + h * DD;   // k = lane
    const u16* K1 = K0 + (size_t)64 * EE;                            // k = lane+64

    float e0 = 0.f, e1 = 0.f;
    #pragma unroll
    for (int d = 0; d < DD; ++d) {
        const float qv = bf2f(Qr[d]);
        e0 += qv * bf2f(K0[d]);
        e1 += qv * bf2f(K1[d]);
    }

    // ref: energy = where(mask==0, -1e20, energy); attn = softmax(energy/32)
    const float scale = 1.0f / 32.0f;
    const float m0 = mask[q * LL + lane];
    const float m1 = mask[q * LL + lane + 64];
    e0 = (m0 == 0.f ? -1.0e20f : e0) * scale;
    e1 = (m1 == 0.f ? -1.0e20f : e1) * scale;

    float m = fmaxf(e0, e1);
    #pragma unroll
    for (int off = 32; off >= 1; off >>= 1) m = fmaxf(m, __shfl_xor(m, off));
    const float p0 = __expf(e0 - m), p1 = __expf(e1 - m);
    float sum = p0 + p1;
    #pragma unroll
    for (int off = 32; off >= 1; off >>= 1) sum += __shfl_xor(sum, off);
    const float inv = 1.0f / sum;
    p[lane]      = p0 * inv;
    p[lane + 64] = p1 * inv;
    __syncthreads();

    // PV: lane = d
    const u16* Vb = v_sel + (size_t)s * LL * EE + h * DD + lane;
    float acc = 0.f;
    for (int k = 0; k < LL; ++k)
        acc += p[k] * bf2f(Vb[(size_t)k * EE]);
    wv[((size_t)s * LL + q) * EE + h * DD + lane] = f2bf_rne(acc);
}

// ---------------------------------------------------------------------------
// Kernel 3: out = wv(256x1024, bf16) @ Wo^T + bo, fp32 out. grid (8, 32).
// 1-wave blocks, 32x32 tile, same prefetch double-buffer as proj.
// ---------------------------------------------------------------------------
__global__ __launch_bounds__(64) void outproj_mfma(
    const u16* __restrict__ wv, const float* __restrict__ Wo,
    const float* __restrict__ bo, float* __restrict__ out)
{
    const int lane = threadIdx.x;
    const int lm   = lane & 15, kq = (lane >> 4) * 8;
    const int row0 = blockIdx.x * 32, col0 = blockIdx.y * 32;

    floatx4 acc[2][2] = {};
    const u16*   a0p = wv + (size_t)(row0 + lm) * EE + kq;
    const u16*   a1p = a0p + 16 * EE;
    const float* b0p = Wo + (size_t)(col0 + lm) * EE + kq;
    const float* b1p = b0p + 16 * EE;

    short8 a0 = *(const short8*)a0p;
    short8 a1 = *(const short8*)a1p;
    short8 b0 = frag_from_f32(b0p);
    short8 b1 = frag_from_f32(b1p);
    for (int k0 = 32; k0 < EE; k0 += 32) {
        short8 na0 = *(const short8*)(a0p + k0);
        short8 na1 = *(const short8*)(a1p + k0);
        short8 nb0 = frag_from_f32(b0p + k0);
        short8 nb1 = frag_from_f32(b1p + k0);
        acc[0][0] = __builtin_amdgcn_mfma_f32_16x16x32_bf16(a0, b0, acc[0][0], 0, 0, 0);
        acc[0][1] = __builtin_amdgcn_mfma_f32_16x16x32_bf16(a0, b1, acc[0][1], 0, 0, 0);
        acc[1][0] = __builtin_amdgcn_mfma_f32_16x16x32_bf16(a1, b0, acc[1][0], 0, 0, 0);
        acc[1][1] = __builtin_amdgcn_mfma_f32_16x16x32_bf16(a1, b1, acc[1][1], 0, 0, 0);
        a0 = na0; a1 = na1; b0 = nb0; b1 = nb1;
    }
    acc[0][0] = __builtin_amdgcn_mfma_f32_16x16x32_bf16(a0, b0, acc[0][0], 0, 0, 0);
    acc[0][1] = __builtin_amdgcn_mfma_f32_16x16x32_bf16(a0, b1, acc[0][1], 0, 0, 0);
    acc[1][0] = __builtin_amdgcn_mfma_f32_16x16x32_bf16(a1, b0, acc[1][0], 0, 0, 0);
    acc[1][1] = __builtin_amdgcn_mfma_f32_16x16x32_bf16(a1, b1, acc[1][1], 0, 0, 0);

    const int rbase = (lane >> 4) * 4;
    #pragma unroll
    for (int i = 0; i < 2; ++i)
        #pragma unroll
        for (int j = 0; j < 2; ++j) {
            const int ccol = col0 + j * 16 + lm;
            const float bb = bo[ccol];
            #pragma unroll
            for (int r = 0; r < 4; ++r) {
                const int crow = row0 + i * 16 + rbase + r;
                out[(size_t)crow * EE + ccol] = acc[i][j][r] + bb;
            }
        }
}

extern "C" void kernel_launch(void* const* d_in, const int* in_sizes, int n_in,
                              void* d_out, int out_size, void* d_ws, size_t ws_size,
                              hipStream_t stream) {
    const float* values = (const float*)d_in[0];
    const float* keys   = (const float*)d_in[1];
    const float* query  = (const float*)d_in[2];
    const float* mask   = (const float*)d_in[3];
    const float* Wv     = (const float*)d_in[4];
    const float* bv     = (const float*)d_in[5];
    const float* Wk     = (const float*)d_in[6];
    const float* bk     = (const float*)d_in[7];
    const float* Wq     = (const float*)d_in[8];
    const float* bq     = (const float*)d_in[9];
    const float* Wo     = (const float*)d_in[10];
    const float* bo     = (const float*)d_in[11];
    const int*   tok    = (const int*)d_in[12];
    const int*   sidx   = (const int*)d_in[13];
    float* out = (float*)d_out;

    const size_t LE = (size_t)LL * EE;   // 131072 elems
    u16* q_sel = (u16*)d_ws;             // L*E        bf16
    u16* k_sel = q_sel + LE;             // S*L*E
    u16* v_sel = k_sel + SS * LE;        // S*L*E
    u16* wv    = v_sel + SS * LE;        // S*L*E      (total ws: 1.75 MB)

    proj_mfma<<<dim3(4, 32, 5), 64, 0, stream>>>(
        values, keys, query, Wv, bv, Wk, bk, Wq, bq, tok, sidx,
        q_sel, k_sel, v_sel);

    attn_simple<<<dim3(128, 16, 2), 64, 0, stream>>>(
        q_sel, k_sel, v_sel, mask, wv);

    outproj_mfma<<<dim3(8, 32, 1), 64, 0, stream>>>(
        wv, Wo, bo, out);
}